// Round 12
// baseline (173.615 us; speedup 1.0000x reference)
//
#include <hip/hip_runtime.h>
#include <math.h>

// Problem constants
#define B_   16
#define C_   128
#define H_   32
#define W_   32
#define D_   64
#define K_   8192
#define HW_  (H_*W_)       // 1024
#define N_   (B_*HW_)      // 16384

// MFMA sweep config — R12: whole split staged once, zero in-loop barriers
#define CS      32         // code splits (grid.y)
#define CPB     (K_/CS)    // 256 codes per block
#define NT      (CPB/16)   // 16 t-steps
#define ROWS_PB 256        // rows per block (4 waves x 64 rows)
// Worst-case bf16 screen error bound; 0.12 margin, E[cands/row] ~ 1.9 (R5-verified).
#define MARGIN  0.12f
#define CAND_CAP 32

typedef short v8s __attribute__((ext_vector_type(8)));
typedef float v4f __attribute__((ext_vector_type(4)));

__device__ __forceinline__ short f2bf(float f) {   // RNE fp32 -> bf16
    union { float fv; unsigned u; } cv; cv.fv = f;
    unsigned u = cv.u;
    unsigned rnd = ((u >> 16) & 1u) + 0x7fffu;
    return (short)((u + rnd) >> 16);
}

// async 16B global->LDS (gfx950). Per-wave: uniform base + lane*16.
#define GLOAD_LDS16(gp, lp) __builtin_amdgcn_global_load_lds( \
    (const __attribute__((address_space(1))) unsigned int*)(gp), \
    (__attribute__((address_space(3))) unsigned int*)(lp), 16, 0, 0)

// Exact fp32 score, bit-identical to the R2 kernel that matched the reference.
__device__ __forceinline__ float exact_score(const float4* __restrict__ zr,
                                             const float* __restrict__ embed,
                                             float h, int k)
{
    const float4* ep = (const float4*)(embed + (size_t)k * D_);
    float sa = 0.f, sb = 0.f;
    #pragma unroll
    for (int d4 = 0; d4 < 16; d4 += 2) {
        float4 ea = ep[d4], eb = ep[d4 + 1];
        sa += ea.x*zr[d4].x + ea.y*zr[d4].y + ea.z*zr[d4].z + ea.w*zr[d4].w;
        sb += eb.x*zr[d4+1].x + eb.y*zr[d4+1].y + eb.z*zr[d4+1].z + eb.w*zr[d4+1].w;
    }
    return (sa + sb) - h;
}

// ---- Kernel 1 (fused): blocks [0,256): 1x1 conv+BN -> ze fp32 + zbf bf16;
//      blocks [256,768): embed -> XOR-swizzled bf16 ebs + hn.
//      ebs: code k, 16B-chunk slot p holds original chunk j = p ^ (k&7).
__global__ __launch_bounds__(256) void k_projprep(
    const float* __restrict__ z, const float* __restrict__ pw,
    const float* __restrict__ pb, const float* __restrict__ gamma,
    const float* __restrict__ beta, const float* __restrict__ rmean,
    const float* __restrict__ rvar, const float* __restrict__ embed,
    float* __restrict__ ze, short* __restrict__ zbf,
    short* __restrict__ ebs, float* __restrict__ hn)
{
    __shared__ float zt[64][132];
    __shared__ float wl[64][132];
    const int tid = threadIdx.x;

    if (blockIdx.x >= 256) {
        // ---- prep: 512 blocks, t in [0, K*16) ----
        int t = (blockIdx.x - 256) * 256 + tid;
        float4 v = ((const float4*)embed)[t];
        float s = v.x*v.x + v.y*v.y + v.z*v.z + v.w*v.w;
        s += __shfl_xor(s, 1);
        s += __shfl_xor(s, 2);
        s += __shfl_xor(s, 4);
        s += __shfl_xor(s, 8);
        const int k = t >> 4, p = t & 15;
        if (p == 0) hn[k] = 0.5f * s;
        if (p < 8) {
            const int j = p ^ (k & 7);                  // XOR swizzle
            const float* src = embed + (size_t)k * D_ + j * 8;
            v8s o;
            #pragma unroll
            for (int i = 0; i < 8; ++i) o[i] = f2bf(src[i]);
            *(v8s*)(ebs + (size_t)k * D_ + p * 8) = o;
        }
        return;
    }

    // ---- proj: 256 blocks (numerics untouched since R2-lineage) ----
    const int n0  = blockIdx.x * 64;
    const int b   = n0 / HW_;
    const int hw0 = n0 % HW_;
    const float* zb = z + (size_t)b * C_ * HW_ + hw0;

    #pragma unroll
    for (int it = 0; it < 32; ++it) {
        int flat = tid + 256 * it;
        int c = flat >> 6, p = flat & 63;
        zt[p][c] = zb[c * HW_ + p];
    }
    #pragma unroll
    for (int it = 0; it < 32; ++it) {
        int flat = tid + 256 * it;
        int d = flat >> 7, c = flat & 127;
        wl[d][c] = pw[d * C_ + c];
    }
    __syncthreads();

    const int tp = tid & 15;
    const int td = tid >> 4;
    float acc[4][4] = {};
    #pragma unroll
    for (int c4 = 0; c4 < 32; ++c4) {
        float4 zv[4], wv[4];
        #pragma unroll
        for (int i = 0; i < 4; ++i) zv[i] = *(const float4*)&zt[4*tp + i][4*c4];
        #pragma unroll
        for (int j = 0; j < 4; ++j) wv[j] = *(const float4*)&wl[4*td + j][4*c4];
        #pragma unroll
        for (int i = 0; i < 4; ++i)
            #pragma unroll
            for (int j = 0; j < 4; ++j)
                acc[i][j] += zv[i].x*wv[j].x + zv[i].y*wv[j].y
                           + zv[i].z*wv[j].z + zv[i].w*wv[j].w;
    }

    float sc[4], bi[4];
    #pragma unroll
    for (int j = 0; j < 4; ++j) {
        int d = 4*td + j;
        float s = gamma[d] / sqrtf(rvar[d] + 1e-5f);
        sc[j] = s;
        bi[j] = pb[d] * s + beta[d] - rmean[d] * s;
    }
    #pragma unroll
    for (int i = 0; i < 4; ++i) {
        int n = n0 + 4*tp + i;
        float4 o;
        o.x = acc[i][0]*sc[0] + bi[0];
        o.y = acc[i][1]*sc[1] + bi[1];
        o.z = acc[i][2]*sc[2] + bi[2];
        o.w = acc[i][3]*sc[3] + bi[3];
        *(float4*)&ze[(size_t)n * D_ + 4*td] = o;
        short4 ob;
        ob.x = f2bf(o.x); ob.y = f2bf(o.y); ob.z = f2bf(o.z); ob.w = f2bf(o.w);
        *(short4*)&zbf[(size_t)n * D_ + 4*td] = ob;
    }
}

// ---- Kernel 2: MFMA bf16 sweep — whole split in LDS, single barrier ------
template<bool PUSH>
__global__ __launch_bounds__(256) void k_sweep(
    const short* __restrict__ zbf, const short* __restrict__ ebs,
    const float* __restrict__ hn, float* __restrict__ pbest,
    const float* __restrict__ Vm, int* __restrict__ cnt,
    int* __restrict__ cand)
{
    __shared__ short eb[CPB * 64];    // 32 KB — entire split, swizzled
    __shared__ float hl[CPB];         // 1 KB
    const int tid  = threadIdx.x;
    const int lane = tid & 63;
    const int wv   = tid >> 6;
    const int q    = lane >> 4;
    const int l15  = lane & 15;
    const int m8   = l15 & 7;         // == (local code)&7 for this lane
    const int rowBase = blockIdx.x * ROWS_PB + wv * 64;
    const int code0   = blockIdx.y * CPB;

    // stage entire split: linear 32 KB copy (async, no VGPR round-trip)
    {
        const char* s_ = (const char*)(ebs + (size_t)code0 * 64);
        char* l_ = (char*)&eb[0];
        #pragma unroll
        for (int i = 0; i < 8; ++i) {
            int seg = (wv * 8 + i) * 1024 + lane * 16;
            GLOAD_LDS16(s_ + seg, l_ + seg);
        }
        hl[tid] = hn[code0 + tid];    // 256 threads, 256 values
    }

    // A fragments: A[m=l15][k=f*32+q*8+j]  (R8-identical) — overlaps staging
    v8s A[4][2];
    #pragma unroll
    for (int rt = 0; rt < 4; ++rt)
        #pragma unroll
        for (int f = 0; f < 2; ++f)
            A[rt][f] = *(const v8s*)(zbf + (size_t)(rowBase + rt*16 + l15) * D_
                                      + f*32 + q*8);

    float best[4][4];
    float vm[4][4];
    if (PUSH) {
        #pragma unroll
        for (int rt = 0; rt < 4; ++rt)
            #pragma unroll
            for (int r = 0; r < 4; ++r)
                vm[rt][r] = Vm[rowBase + rt*16 + q*4 + r];
    } else {
        #pragma unroll
        for (int rt = 0; rt < 4; ++rt)
            #pragma unroll
            for (int r = 0; r < 4; ++r) best[rt][r] = -INFINITY;
    }

    // lane-constant swizzled LDS read offsets (shorts):
    // B0 (d 0..31) chunk j=q -> slot q^m8 ; B1 (d 32..63) j=q^4 -> slot (q^m8)^4
    const int rb0 = l15 * 64 + ((q ^ m8) * 8);
    const int rb1 = l15 * 64 + (((q ^ m8) ^ 4) * 8);

    __syncthreads();    // the ONLY barrier

    #pragma unroll 1    // I$: ~2-4 KB inner body (R7 lesson)
    for (int tc = 0; tc < 2; ++tc) {
        #pragma unroll
        for (int ti = 0; ti < 8; ++ti) {
            const int t = tc * 8 + ti;
            v8s B0 = *(const v8s*)(&eb[0] + rb0 + t * 1024);
            v8s B1 = *(const v8s*)(&eb[0] + rb1 + t * 1024);
            const float mh = -hl[t * 16 + l15];
            #pragma unroll
            for (int rt = 0; rt < 4; ++rt) {
                v4f c = {mh, mh, mh, mh};
                c = __builtin_amdgcn_mfma_f32_16x16x32_bf16(A[rt][0], B0, c, 0, 0, 0);
                c = __builtin_amdgcn_mfma_f32_16x16x32_bf16(A[rt][1], B1, c, 0, 0, 0);
                if (!PUSH) {
                    #pragma unroll
                    for (int r = 0; r < 4; ++r) best[rt][r] = fmaxf(best[rt][r], c[r]);
                } else {
                    bool a0 = c[0] > vm[rt][0];
                    bool a1 = c[1] > vm[rt][1];
                    bool a2 = c[2] > vm[rt][2];
                    bool a3 = c[3] > vm[rt][3];
                    if (a0 | a1 | a2 | a3) {
                        const int code = code0 + t * 16 + l15;
                        const int row0 = rowBase + rt*16 + q*4;
                        #pragma unroll
                        for (int r = 0; r < 4; ++r) {
                            if (c[r] > vm[rt][r]) {
                                int s = atomicAdd(&cnt[row0 + r], 1);
                                if (s < CAND_CAP) cand[(row0 + r) * CAND_CAP + s] = code;
                            }
                        }
                    }
                }
            }
        }
    }

    if (!PUSH) {
        #pragma unroll
        for (int rt = 0; rt < 4; ++rt)
            #pragma unroll
            for (int r = 0; r < 4; ++r) {
                float v = best[rt][r];
                v = fmaxf(v, __shfl_xor(v, 1));
                v = fmaxf(v, __shfl_xor(v, 2));
                v = fmaxf(v, __shfl_xor(v, 4));
                v = fmaxf(v, __shfl_xor(v, 8));
                if (l15 == 0)
                    pbest[(size_t)blockIdx.y * N_ + rowBase + rt*16 + q*4 + r] = v;
            }
    }
}

// ---- Kernel 3: combine splits -> threshold, zero counters + diff scalar --
__global__ __launch_bounds__(256) void k_comb(const float* __restrict__ pbest,
                                              float* __restrict__ Vm,
                                              int* __restrict__ cnt,
                                              float* __restrict__ outDiff)
{
    int n = blockIdx.x * 256 + threadIdx.x;
    float v = -INFINITY;
    #pragma unroll
    for (int s = 0; s < CS; ++s) v = fmaxf(v, pbest[(size_t)s * N_ + n]);
    Vm[n] = v - MARGIN;
    cnt[n] = 0;
    if (n == 0) *outDiff = 0.f;
}

// ---- Kernel 4: exact fp32 rescore + outputs + diff (atomic) --------------
__global__ __launch_bounds__(64) void k_pick(
    const int* __restrict__ cnt, const int* __restrict__ cand,
    const float* __restrict__ embed, const float* __restrict__ hn,
    const float* __restrict__ ze, float* __restrict__ out0,
    float* __restrict__ outIdx, float* __restrict__ outDiff)
{
    const int tid = threadIdx.x;
    const int n   = blockIdx.x * 64 + tid;

    float4 zr[16];
    const float4* zp = (const float4*)(ze + (size_t)n * D_);
    #pragma unroll
    for (int i = 0; i < 16; ++i) zr[i] = zp[i];

    const int m = cnt[n];
    float best = -INFINITY;
    int   bidx = 0x7fffffff;
    if (m == 0 || m > CAND_CAP) {
        // safety net: screen anomaly -> full exact scan, ascending k (== R2)
        for (int k = 0; k < K_; ++k) {
            float s = exact_score(zr, embed, hn[k], k);
            if (s > best) { best = s; bidx = k; }
        }
    } else {
        for (int i = 0; i < m; ++i) {
            int k = cand[n * CAND_CAP + i];
            float s = exact_score(zr, embed, hn[k], k);
            if (s > best || (s == best && k < bidx)) { best = s; bidx = k; }
        }
    }
    if (bidx == 0x7fffffff) bidx = 0;
    outIdx[n] = (float)bidx;

    const float4* eq = (const float4*)(embed + (size_t)bidx * D_);
    const int b = n >> 10, hw = n & 1023;
    float* o = out0 + (size_t)b * (D_ * HW_) + hw;

    float local = 0.f;
    #pragma unroll
    for (int d4 = 0; d4 < 16; ++d4) {
        float4 e = eq[d4], zv = zr[d4];
        float dx = e.x - zv.x, dy = e.y - zv.y, dz = e.z - zv.z, dw = e.w - zv.w;
        local += dx*dx + dy*dy + dz*dz + dw*dw;
        o[(4*d4 + 0) * HW_] = e.x;
        o[(4*d4 + 1) * HW_] = e.y;
        o[(4*d4 + 2) * HW_] = e.z;
        o[(4*d4 + 3) * HW_] = e.w;
    }

    local += __shfl_xor(local, 1);
    local += __shfl_xor(local, 2);
    local += __shfl_xor(local, 4);
    local += __shfl_xor(local, 8);
    local += __shfl_xor(local, 16);
    local += __shfl_xor(local, 32);
    if (tid == 0) atomicAdd(outDiff, local * (12.5f / (float)(N_ * D_)));
}

extern "C" void kernel_launch(void* const* d_in, const int* in_sizes, int n_in,
                              void* d_out, int out_size, void* d_ws, size_t ws_size,
                              hipStream_t stream)
{
    const float* z     = (const float*)d_in[0];
    const float* pw    = (const float*)d_in[1];
    const float* pb    = (const float*)d_in[2];
    const float* gamma = (const float*)d_in[3];
    const float* beta  = (const float*)d_in[4];
    const float* rmean = (const float*)d_in[5];
    const float* rvar  = (const float*)d_in[6];
    const float* embed = (const float*)d_in[7];

    float* out = (float*)d_out;
    float* out0    = out;                     // [B,D,H,W]
    float* outDiff = out + (size_t)N_ * D_;   // scalar
    float* outIdx  = outDiff + 1;             // [B,H,W]

    // Workspace layout
    float* ws    = (float*)d_ws;
    float* ze    = ws;                                   // N*64 f   (4 MB)
    short* zbf   = (short*)(ze + (size_t)N_ * D_);       // N*64 s   (2 MB)
    short* ebs   = zbf + (size_t)N_ * D_;                // K*64 s   (1 MB)
    float* hn    = (float*)(ebs + (size_t)K_ * D_);      // K        (32 KB)
    float* pbest = hn + K_;                              // CS*N     (2 MB)
    float* Vm    = pbest + (size_t)CS * N_;              // N        (64 KB)
    int*   cnt   = (int*)(Vm + N_);                      // N        (64 KB)
    int*   cand  = cnt + N_;                             // N*32     (2 MB)

    k_projprep<<<256 + 512, 256, 0, stream>>>(z, pw, pb, gamma, beta, rmean,
                                              rvar, embed, ze, zbf, ebs, hn);
    k_sweep<false><<<dim3(N_ / ROWS_PB, CS), 256, 0, stream>>>(
        zbf, ebs, hn, pbest, nullptr, nullptr, nullptr);
    k_comb <<<N_ / 256, 256, 0, stream>>>(pbest, Vm, cnt, outDiff);
    k_sweep<true><<<dim3(N_ / ROWS_PB, CS), 256, 0, stream>>>(
        zbf, ebs, hn, pbest, Vm, cnt, cand);
    k_pick <<<N_ / 64, 64, 0, stream>>>(cnt, cand, embed, hn, ze, out0,
                                        outIdx, outDiff);
}

// Round 13
// 168.609 us; speedup vs baseline: 1.0297x; 1.0297x over previous
//
#include <hip/hip_runtime.h>
#include <math.h>

// Problem constants
#define B_   16
#define C_   128
#define H_   32
#define W_   32
#define D_   64
#define K_   8192
#define HW_  (H_*W_)       // 1024
#define N_   (B_*HW_)      // 16384

// MFMA sweep config — whole split staged once, zero in-loop barriers (R12)
#define CS      32         // code splits (grid.y)
#define CPB     (K_/CS)    // 256 codes per block
#define ROWS_PB 256        // rows per block (4 waves x 64 rows)
// Worst-case bf16 screen error bound; 0.12 margin, E[cands/row] ~ 1.9 (R5-verified).
#define MARGIN  0.12f
#define CAND_CAP 32

typedef short v8s __attribute__((ext_vector_type(8)));
typedef float v4f __attribute__((ext_vector_type(4)));

__device__ __forceinline__ short f2bf(float f) {   // RNE fp32 -> bf16
    union { float fv; unsigned u; } cv; cv.fv = f;
    unsigned u = cv.u;
    unsigned rnd = ((u >> 16) & 1u) + 0x7fffu;
    return (short)((u + rnd) >> 16);
}

// async 16B global->LDS (gfx950). Per-wave: uniform base + lane*16.
#define GLOAD_LDS16(gp, lp) __builtin_amdgcn_global_load_lds( \
    (const __attribute__((address_space(1))) unsigned int*)(gp), \
    (__attribute__((address_space(3))) unsigned int*)(lp), 16, 0, 0)

// Exact fp32 score, bit-identical to the R2 kernel that matched the reference.
__device__ __forceinline__ float exact_score(const float4* __restrict__ zr,
                                             const float* __restrict__ embed,
                                             float h, int k)
{
    const float4* ep = (const float4*)(embed + (size_t)k * D_);
    float sa = 0.f, sb = 0.f;
    #pragma unroll
    for (int d4 = 0; d4 < 16; d4 += 2) {
        float4 ea = ep[d4], eb = ep[d4 + 1];
        sa += ea.x*zr[d4].x + ea.y*zr[d4].y + ea.z*zr[d4].z + ea.w*zr[d4].w;
        sb += eb.x*zr[d4+1].x + eb.y*zr[d4+1].y + eb.z*zr[d4+1].z + eb.w*zr[d4+1].w;
    }
    return (sa + sb) - h;
}

// ---- Kernel 1 (fused): blocks [0,256): 1x1 conv+BN -> ze fp32 + zbfT bf16
//      (TILED: 64-row group g, load-slot i=(r>>4)*2+(d>>5), lane=((d>>3)&3)*16
//       +(r&15), element j=d&7 -> zbfT[g*4096 + i*512 + lane*8 + j]);
//      blocks [256,768): embed -> XOR-swizzled bf16 ebs + hn.
__global__ __launch_bounds__(256) void k_projprep(
    const float* __restrict__ z, const float* __restrict__ pw,
    const float* __restrict__ pb, const float* __restrict__ gamma,
    const float* __restrict__ beta, const float* __restrict__ rmean,
    const float* __restrict__ rvar, const float* __restrict__ embed,
    float* __restrict__ ze, short* __restrict__ zbfT,
    short* __restrict__ ebs, float* __restrict__ hn)
{
    __shared__ float zt[64][132];
    __shared__ float wl[64][132];
    const int tid = threadIdx.x;

    if (blockIdx.x >= 256) {
        // ---- prep: 512 blocks, t in [0, K*16) ----
        int t = (blockIdx.x - 256) * 256 + tid;
        float4 v = ((const float4*)embed)[t];
        float s = v.x*v.x + v.y*v.y + v.z*v.z + v.w*v.w;
        s += __shfl_xor(s, 1);
        s += __shfl_xor(s, 2);
        s += __shfl_xor(s, 4);
        s += __shfl_xor(s, 8);
        const int k = t >> 4, p = t & 15;
        if (p == 0) hn[k] = 0.5f * s;
        if (p < 8) {
            const int j = p ^ (k & 7);                  // XOR swizzle
            const float* src = embed + (size_t)k * D_ + j * 8;
            v8s o;
            #pragma unroll
            for (int i = 0; i < 8; ++i) o[i] = f2bf(src[i]);
            *(v8s*)(ebs + (size_t)k * D_ + p * 8) = o;
        }
        return;
    }

    // ---- proj: 256 blocks (numerics untouched since R2-lineage) ----
    const int n0  = blockIdx.x * 64;
    const int b   = n0 / HW_;
    const int hw0 = n0 % HW_;
    const float* zb = z + (size_t)b * C_ * HW_ + hw0;

    #pragma unroll
    for (int it = 0; it < 32; ++it) {
        int flat = tid + 256 * it;
        int c = flat >> 6, p = flat & 63;
        zt[p][c] = zb[c * HW_ + p];
    }
    #pragma unroll
    for (int it = 0; it < 32; ++it) {
        int flat = tid + 256 * it;
        int d = flat >> 7, c = flat & 127;
        wl[d][c] = pw[d * C_ + c];
    }
    __syncthreads();

    const int tp = tid & 15;
    const int td = tid >> 4;
    float acc[4][4] = {};
    #pragma unroll
    for (int c4 = 0; c4 < 32; ++c4) {
        float4 zv[4], wv[4];
        #pragma unroll
        for (int i = 0; i < 4; ++i) zv[i] = *(const float4*)&zt[4*tp + i][4*c4];
        #pragma unroll
        for (int j = 0; j < 4; ++j) wv[j] = *(const float4*)&wl[4*td + j][4*c4];
        #pragma unroll
        for (int i = 0; i < 4; ++i)
            #pragma unroll
            for (int j = 0; j < 4; ++j)
                acc[i][j] += zv[i].x*wv[j].x + zv[i].y*wv[j].y
                           + zv[i].z*wv[j].z + zv[i].w*wv[j].w;
    }

    float sc[4], bi[4];
    #pragma unroll
    for (int j = 0; j < 4; ++j) {
        int d = 4*td + j;
        float s = gamma[d] / sqrtf(rvar[d] + 1e-5f);
        sc[j] = s;
        bi[j] = pb[d] * s + beta[d] - rmean[d] * s;
    }
    // tiled-store constants for this thread (dims d = 4*td..4*td+3):
    short* tbase = zbfT + (size_t)blockIdx.x * 4096;
    const int islot_base = (tp >> 2) * 2 + (td >> 3);   // r>>4 = tp>>2 (no carry)
    const int lane_hi    = ((td >> 1) & 3) * 16;        // (d>>3)&3
    const int el0        = 4 * (td & 1);                // d&7 start
    #pragma unroll
    for (int i = 0; i < 4; ++i) {
        int n = n0 + 4*tp + i;
        float4 o;
        o.x = acc[i][0]*sc[0] + bi[0];
        o.y = acc[i][1]*sc[1] + bi[1];
        o.z = acc[i][2]*sc[2] + bi[2];
        o.w = acc[i][3]*sc[3] + bi[3];
        *(float4*)&ze[(size_t)n * D_ + 4*td] = o;
        short4 ob;
        ob.x = f2bf(o.x); ob.y = f2bf(o.y); ob.z = f2bf(o.z); ob.w = f2bf(o.w);
        const int lane = lane_hi + ((4*tp + i) & 15);   // r&15
        *(short4*)(tbase + islot_base * 512 + lane * 8 + el0) = ob;
    }
}

// ---- Kernel 2: MFMA bf16 sweep — whole split in LDS, single barrier,
//      A-fragments from TILED zbfT (coalesced 1KB wave reads, R13) ---------
template<bool PUSH>
__global__ __launch_bounds__(256) void k_sweep(
    const short* __restrict__ zbfT, const short* __restrict__ ebs,
    const float* __restrict__ hn, float* __restrict__ pbest,
    const float* __restrict__ Vm, int* __restrict__ cnt,
    int* __restrict__ cand)
{
    __shared__ short eb[CPB * 64];    // 32 KB — entire split, swizzled
    __shared__ float hl[CPB];         // 1 KB
    const int tid  = threadIdx.x;
    const int lane = tid & 63;
    const int wv   = tid >> 6;
    const int q    = lane >> 4;
    const int l15  = lane & 15;
    const int m8   = l15 & 7;         // == (local code)&7 for this lane
    const int rowBase = blockIdx.x * ROWS_PB + wv * 64;
    const int code0   = blockIdx.y * CPB;

    // stage entire split: linear 32 KB copy (async, no VGPR round-trip)
    {
        const char* s_ = (const char*)(ebs + (size_t)code0 * 64);
        char* l_ = (char*)&eb[0];
        #pragma unroll
        for (int i = 0; i < 8; ++i) {
            int seg = (wv * 8 + i) * 1024 + lane * 16;
            GLOAD_LDS16(s_ + seg, l_ + seg);
        }
        hl[tid] = hn[code0 + tid];    // 256 threads, 256 values
    }

    // A fragments from tiled zbfT: 8 coalesced b128 per lane
    const short* aw = zbfT + (size_t)(blockIdx.x * 4 + wv) * 4096;
    v8s A[4][2];
    #pragma unroll
    for (int i = 0; i < 8; ++i)
        A[i >> 1][i & 1] = *(const v8s*)(aw + i * 512 + lane * 8);

    float best[4][4];
    float vm[4][4];
    if (PUSH) {
        #pragma unroll
        for (int rt = 0; rt < 4; ++rt)
            #pragma unroll
            for (int r = 0; r < 4; ++r)
                vm[rt][r] = Vm[rowBase + rt*16 + q*4 + r];
    } else {
        #pragma unroll
        for (int rt = 0; rt < 4; ++rt)
            #pragma unroll
            for (int r = 0; r < 4; ++r) best[rt][r] = -INFINITY;
    }

    // lane-constant swizzled LDS read offsets (shorts):
    // B0 (d 0..31) chunk j=q -> slot q^m8 ; B1 (d 32..63) j=q^4 -> slot (q^m8)^4
    const int rb0 = l15 * 64 + ((q ^ m8) * 8);
    const int rb1 = l15 * 64 + (((q ^ m8) ^ 4) * 8);

    __syncthreads();    // the ONLY barrier

    #pragma unroll 1    // I$: keep body small (R7 lesson)
    for (int tc = 0; tc < 2; ++tc) {
        #pragma unroll
        for (int ti = 0; ti < 8; ++ti) {
            const int t = tc * 8 + ti;
            v8s B0 = *(const v8s*)(&eb[0] + rb0 + t * 1024);
            v8s B1 = *(const v8s*)(&eb[0] + rb1 + t * 1024);
            const float mh = -hl[t * 16 + l15];
            #pragma unroll
            for (int rt = 0; rt < 4; ++rt) {
                v4f c = {mh, mh, mh, mh};
                c = __builtin_amdgcn_mfma_f32_16x16x32_bf16(A[rt][0], B0, c, 0, 0, 0);
                c = __builtin_amdgcn_mfma_f32_16x16x32_bf16(A[rt][1], B1, c, 0, 0, 0);
                if (!PUSH) {
                    #pragma unroll
                    for (int r = 0; r < 4; ++r) best[rt][r] = fmaxf(best[rt][r], c[r]);
                } else {
                    bool a0 = c[0] > vm[rt][0];
                    bool a1 = c[1] > vm[rt][1];
                    bool a2 = c[2] > vm[rt][2];
                    bool a3 = c[3] > vm[rt][3];
                    if (a0 | a1 | a2 | a3) {
                        const int code = code0 + t * 16 + l15;
                        const int row0 = rowBase + rt*16 + q*4;
                        #pragma unroll
                        for (int r = 0; r < 4; ++r) {
                            if (c[r] > vm[rt][r]) {
                                int s = atomicAdd(&cnt[row0 + r], 1);
                                if (s < CAND_CAP) cand[(row0 + r) * CAND_CAP + s] = code;
                            }
                        }
                    }
                }
            }
        }
    }

    if (!PUSH) {
        #pragma unroll
        for (int rt = 0; rt < 4; ++rt)
            #pragma unroll
            for (int r = 0; r < 4; ++r) {
                float v = best[rt][r];
                v = fmaxf(v, __shfl_xor(v, 1));
                v = fmaxf(v, __shfl_xor(v, 2));
                v = fmaxf(v, __shfl_xor(v, 4));
                v = fmaxf(v, __shfl_xor(v, 8));
                if (l15 == 0)
                    pbest[(size_t)blockIdx.y * N_ + rowBase + rt*16 + q*4 + r] = v;
            }
    }
}

// ---- Kernel 3: combine splits -> threshold, zero counters + diff scalar --
__global__ __launch_bounds__(256) void k_comb(const float* __restrict__ pbest,
                                              float* __restrict__ Vm,
                                              int* __restrict__ cnt,
                                              float* __restrict__ outDiff)
{
    int n = blockIdx.x * 256 + threadIdx.x;
    float v = -INFINITY;
    #pragma unroll
    for (int s = 0; s < CS; ++s) v = fmaxf(v, pbest[(size_t)s * N_ + n]);
    Vm[n] = v - MARGIN;
    cnt[n] = 0;
    if (n == 0) *outDiff = 0.f;
}

// ---- Kernel 4: exact fp32 rescore + outputs + diff (atomic) --------------
__global__ __launch_bounds__(64) void k_pick(
    const int* __restrict__ cnt, const int* __restrict__ cand,
    const float* __restrict__ embed, const float* __restrict__ hn,
    const float* __restrict__ ze, float* __restrict__ out0,
    float* __restrict__ outIdx, float* __restrict__ outDiff)
{
    const int tid = threadIdx.x;
    const int n   = blockIdx.x * 64 + tid;

    float4 zr[16];
    const float4* zp = (const float4*)(ze + (size_t)n * D_);
    #pragma unroll
    for (int i = 0; i < 16; ++i) zr[i] = zp[i];

    const int m = cnt[n];
    float best = -INFINITY;
    int   bidx = 0x7fffffff;
    if (m == 0 || m > CAND_CAP) {
        // safety net: screen anomaly -> full exact scan, ascending k (== R2)
        for (int k = 0; k < K_; ++k) {
            float s = exact_score(zr, embed, hn[k], k);
            if (s > best) { best = s; bidx = k; }
        }
    } else {
        for (int i = 0; i < m; ++i) {
            int k = cand[n * CAND_CAP + i];
            float s = exact_score(zr, embed, hn[k], k);
            if (s > best || (s == best && k < bidx)) { best = s; bidx = k; }
        }
    }
    if (bidx == 0x7fffffff) bidx = 0;
    outIdx[n] = (float)bidx;

    const float4* eq = (const float4*)(embed + (size_t)bidx * D_);
    const int b = n >> 10, hw = n & 1023;
    float* o = out0 + (size_t)b * (D_ * HW_) + hw;

    float local = 0.f;
    #pragma unroll
    for (int d4 = 0; d4 < 16; ++d4) {
        float4 e = eq[d4], zv = zr[d4];
        float dx = e.x - zv.x, dy = e.y - zv.y, dz = e.z - zv.z, dw = e.w - zv.w;
        local += dx*dx + dy*dy + dz*dz + dw*dw;
        o[(4*d4 + 0) * HW_] = e.x;
        o[(4*d4 + 1) * HW_] = e.y;
        o[(4*d4 + 2) * HW_] = e.z;
        o[(4*d4 + 3) * HW_] = e.w;
    }

    local += __shfl_xor(local, 1);
    local += __shfl_xor(local, 2);
    local += __shfl_xor(local, 4);
    local += __shfl_xor(local, 8);
    local += __shfl_xor(local, 16);
    local += __shfl_xor(local, 32);
    if (tid == 0) atomicAdd(outDiff, local * (12.5f / (float)(N_ * D_)));
}

extern "C" void kernel_launch(void* const* d_in, const int* in_sizes, int n_in,
                              void* d_out, int out_size, void* d_ws, size_t ws_size,
                              hipStream_t stream)
{
    const float* z     = (const float*)d_in[0];
    const float* pw    = (const float*)d_in[1];
    const float* pb    = (const float*)d_in[2];
    const float* gamma = (const float*)d_in[3];
    const float* beta  = (const float*)d_in[4];
    const float* rmean = (const float*)d_in[5];
    const float* rvar  = (const float*)d_in[6];
    const float* embed = (const float*)d_in[7];

    float* out = (float*)d_out;
    float* out0    = out;                     // [B,D,H,W]
    float* outDiff = out + (size_t)N_ * D_;   // scalar
    float* outIdx  = outDiff + 1;             // [B,H,W]

    // Workspace layout
    float* ws    = (float*)d_ws;
    float* ze    = ws;                                   // N*64 f   (4 MB)
    short* zbfT  = (short*)(ze + (size_t)N_ * D_);       // N*64 s   (2 MB, tiled)
    short* ebs   = zbfT + (size_t)N_ * D_;               // K*64 s   (1 MB)
    float* hn    = (float*)(ebs + (size_t)K_ * D_);      // K        (32 KB)
    float* pbest = hn + K_;                              // CS*N     (2 MB)
    float* Vm    = pbest + (size_t)CS * N_;              // N        (64 KB)
    int*   cnt   = (int*)(Vm + N_);                      // N        (64 KB)
    int*   cand  = cnt + N_;                             // N*32     (2 MB)

    k_projprep<<<256 + 512, 256, 0, stream>>>(z, pw, pb, gamma, beta, rmean,
                                              rvar, embed, ze, zbfT, ebs, hn);
    k_sweep<false><<<dim3(N_ / ROWS_PB, CS), 256, 0, stream>>>(
        zbfT, ebs, hn, pbest, nullptr, nullptr, nullptr);
    k_comb <<<N_ / 256, 256, 0, stream>>>(pbest, Vm, cnt, outDiff);
    k_sweep<true><<<dim3(N_ / ROWS_PB, CS), 256, 0, stream>>>(
        zbfT, ebs, hn, pbest, Vm, cnt, cand);
    k_pick <<<N_ / 64, 64, 0, stream>>>(cnt, cand, embed, hn, ze, out0,
                                        outIdx, outDiff);
}

// Round 14
// 157.637 us; speedup vs baseline: 1.1014x; 1.0696x over previous
//
#include <hip/hip_runtime.h>
#include <math.h>

// Problem constants
#define B_   16
#define C_   128
#define H_   32
#define W_   32
#define D_   64
#define K_   8192
#define HW_  (H_*W_)       // 1024
#define N_   (B_*HW_)      // 16384

// MFMA sweep config — whole split staged once, zero in-loop barriers (R12)
#define CS      32         // code splits (grid.y)
#define CPB     (K_/CS)    // 256 codes per block
#define ROWS_PB 256        // rows per block (4 waves x 64 rows)
// Worst-case bf16 screen error bound; 0.12 margin, E[cands/row] ~ 1.9 (R5-verified).
#define MARGIN  0.12f
#define CAND_CAP 32

typedef short v8s __attribute__((ext_vector_type(8)));
typedef float v4f __attribute__((ext_vector_type(4)));

__device__ __forceinline__ short f2bf(float f) {   // RNE fp32 -> bf16
    union { float fv; unsigned u; } cv; cv.fv = f;
    unsigned u = cv.u;
    unsigned rnd = ((u >> 16) & 1u) + 0x7fffu;
    return (short)((u + rnd) >> 16);
}

// async 16B global->LDS (gfx950). Per-wave: uniform base + lane*16.
#define GLOAD_LDS16(gp, lp) __builtin_amdgcn_global_load_lds( \
    (const __attribute__((address_space(1))) unsigned int*)(gp), \
    (__attribute__((address_space(3))) unsigned int*)(lp), 16, 0, 0)

// Exact fp32 score, bit-identical to the R2 kernel that matched the reference.
__device__ __forceinline__ float exact_score(const float4* __restrict__ zr,
                                             const float* __restrict__ embed,
                                             float h, int k)
{
    const float4* ep = (const float4*)(embed + (size_t)k * D_);
    float sa = 0.f, sb = 0.f;
    #pragma unroll
    for (int d4 = 0; d4 < 16; d4 += 2) {
        float4 ea = ep[d4], eb = ep[d4 + 1];
        sa += ea.x*zr[d4].x + ea.y*zr[d4].y + ea.z*zr[d4].z + ea.w*zr[d4].w;
        sb += eb.x*zr[d4+1].x + eb.y*zr[d4+1].y + eb.z*zr[d4+1].z + eb.w*zr[d4+1].w;
    }
    return (sa + sb) - h;
}

// ---- Kernel 1 (fused): blocks [0,256): 1x1 conv+BN -> ze fp32 + zbfT bf16
//      (R14: LDS tiles kept in GLOBAL layout zt[c][p], wl[d][c]; staging is
//       pure float4 copy, conflict-free; compute reads z transposed — the
//       fp32 FMA expression tree is IDENTICAL to R2-lineage);
//      blocks [256,768): embed -> XOR-swizzled bf16 ebs + hn.
__global__ __launch_bounds__(256) void k_projprep(
    const float* __restrict__ z, const float* __restrict__ pw,
    const float* __restrict__ pb, const float* __restrict__ gamma,
    const float* __restrict__ beta, const float* __restrict__ rmean,
    const float* __restrict__ rvar, const float* __restrict__ embed,
    float* __restrict__ ze, short* __restrict__ zbfT,
    short* __restrict__ ebs, float* __restrict__ hn)
{
    __shared__ float zt[128][64];   // [c][p] — straight copy of z tile (32 KB)
    __shared__ float wl[64][128];   // [d][c] — straight copy of W     (32 KB)
    const int tid = threadIdx.x;

    if (blockIdx.x >= 256) {
        // ---- prep: 512 blocks, t in [0, K*16) ----
        int t = (blockIdx.x - 256) * 256 + tid;
        float4 v = ((const float4*)embed)[t];
        float s = v.x*v.x + v.y*v.y + v.z*v.z + v.w*v.w;
        s += __shfl_xor(s, 1);
        s += __shfl_xor(s, 2);
        s += __shfl_xor(s, 4);
        s += __shfl_xor(s, 8);
        const int k = t >> 4, p = t & 15;
        if (p == 0) hn[k] = 0.5f * s;
        if (p < 8) {
            const int j = p ^ (k & 7);                  // XOR swizzle
            const float* src = embed + (size_t)k * D_ + j * 8;
            v8s o;
            #pragma unroll
            for (int i = 0; i < 8; ++i) o[i] = f2bf(src[i]);
            *(v8s*)(ebs + (size_t)k * D_ + p * 8) = o;
        }
        return;
    }

    // ---- proj: 256 blocks ----
    const int n0  = blockIdx.x * 64;
    const int b   = n0 / HW_;
    const int hw0 = n0 % HW_;
    const float* zb = z + (size_t)b * C_ * HW_ + hw0;

    // stage z tile: 2048 float4, straight [c][p] copy (coalesced, conflict-free)
    #pragma unroll
    for (int it = 0; it < 8; ++it) {
        int flat = tid + 256 * it;          // float4 units
        int c = flat >> 4, p4 = flat & 15;
        *(float4*)&zt[c][4*p4] = *(const float4*)&zb[c * HW_ + 4*p4];
    }
    // stage W: 2048 float4, straight [d][c] copy
    #pragma unroll
    for (int it = 0; it < 8; ++it) {
        int flat = tid + 256 * it;
        int d = flat >> 5, c4i = flat & 31;
        *(float4*)&wl[d][4*c4i] = *(const float4*)&pw[d * C_ + 4*c4i];
    }
    __syncthreads();

    const int tp = tid & 15;
    const int td = tid >> 4;
    float acc[4][4] = {};
    #pragma unroll
    for (int c4 = 0; c4 < 32; ++c4) {
        float4 zq[4], wv[4];
        // zq[k][i] = z[pos=4tp+i][c=4c4+k]  (b128 along p in [c][p] layout)
        #pragma unroll
        for (int k = 0; k < 4; ++k) zq[k] = *(const float4*)&zt[4*c4 + k][4*tp];
        #pragma unroll
        for (int j = 0; j < 4; ++j) wv[j] = *(const float4*)&wl[4*td + j][4*c4];
        // identical fp32 expression tree to R2-lineage:
        // zv[i].x==zq[0][i], .y==zq[1][i], .z==zq[2][i], .w==zq[3][i]
        #pragma unroll
        for (int i = 0; i < 4; ++i)
            #pragma unroll
            for (int j = 0; j < 4; ++j)
                acc[i][j] += zq[0][i]*wv[j].x + zq[1][i]*wv[j].y
                           + zq[2][i]*wv[j].z + zq[3][i]*wv[j].w;
    }

    float sc[4], bi[4];
    #pragma unroll
    for (int j = 0; j < 4; ++j) {
        int d = 4*td + j;
        float s = gamma[d] / sqrtf(rvar[d] + 1e-5f);
        sc[j] = s;
        bi[j] = pb[d] * s + beta[d] - rmean[d] * s;
    }
    // tiled-store constants for this thread (dims d = 4*td..4*td+3):
    short* tbase = zbfT + (size_t)blockIdx.x * 4096;
    const int islot_base = (tp >> 2) * 2 + (td >> 3);   // r>>4 = tp>>2 (no carry)
    const int lane_hi    = ((td >> 1) & 3) * 16;        // (d>>3)&3
    const int el0        = 4 * (td & 1);                // d&7 start
    #pragma unroll
    for (int i = 0; i < 4; ++i) {
        int n = n0 + 4*tp + i;
        float4 o;
        o.x = acc[i][0]*sc[0] + bi[0];
        o.y = acc[i][1]*sc[1] + bi[1];
        o.z = acc[i][2]*sc[2] + bi[2];
        o.w = acc[i][3]*sc[3] + bi[3];
        *(float4*)&ze[(size_t)n * D_ + 4*td] = o;
        short4 ob;
        ob.x = f2bf(o.x); ob.y = f2bf(o.y); ob.z = f2bf(o.z); ob.w = f2bf(o.w);
        const int lane = lane_hi + ((4*tp + i) & 15);   // r&15
        *(short4*)(tbase + islot_base * 512 + lane * 8 + el0) = ob;
    }
}

// ---- Kernel 2: MFMA bf16 sweep — whole split in LDS, single barrier,
//      A-fragments from TILED zbfT (coalesced 1KB wave reads, R13) ---------
template<bool PUSH>
__global__ __launch_bounds__(256) void k_sweep(
    const short* __restrict__ zbfT, const short* __restrict__ ebs,
    const float* __restrict__ hn, float* __restrict__ pbest,
    const float* __restrict__ Vm, int* __restrict__ cnt,
    int* __restrict__ cand)
{
    __shared__ short eb[CPB * 64];    // 32 KB — entire split, swizzled
    __shared__ float hl[CPB];         // 1 KB
    const int tid  = threadIdx.x;
    const int lane = tid & 63;
    const int wv   = tid >> 6;
    const int q    = lane >> 4;
    const int l15  = lane & 15;
    const int m8   = l15 & 7;         // == (local code)&7 for this lane
    const int rowBase = blockIdx.x * ROWS_PB + wv * 64;
    const int code0   = blockIdx.y * CPB;

    // stage entire split: linear 32 KB copy (async, no VGPR round-trip)
    {
        const char* s_ = (const char*)(ebs + (size_t)code0 * 64);
        char* l_ = (char*)&eb[0];
        #pragma unroll
        for (int i = 0; i < 8; ++i) {
            int seg = (wv * 8 + i) * 1024 + lane * 16;
            GLOAD_LDS16(s_ + seg, l_ + seg);
        }
        hl[tid] = hn[code0 + tid];    // 256 threads, 256 values
    }

    // A fragments from tiled zbfT: 8 coalesced b128 per lane
    const short* aw = zbfT + (size_t)(blockIdx.x * 4 + wv) * 4096;
    v8s A[4][2];
    #pragma unroll
    for (int i = 0; i < 8; ++i)
        A[i >> 1][i & 1] = *(const v8s*)(aw + i * 512 + lane * 8);

    float best[4][4];
    float vm[4][4];
    if (PUSH) {
        #pragma unroll
        for (int rt = 0; rt < 4; ++rt)
            #pragma unroll
            for (int r = 0; r < 4; ++r)
                vm[rt][r] = Vm[rowBase + rt*16 + q*4 + r];
    } else {
        #pragma unroll
        for (int rt = 0; rt < 4; ++rt)
            #pragma unroll
            for (int r = 0; r < 4; ++r) best[rt][r] = -INFINITY;
    }

    // lane-constant swizzled LDS read offsets (shorts):
    // B0 (d 0..31) chunk j=q -> slot q^m8 ; B1 (d 32..63) j=q^4 -> slot (q^m8)^4
    const int rb0 = l15 * 64 + ((q ^ m8) * 8);
    const int rb1 = l15 * 64 + (((q ^ m8) ^ 4) * 8);

    __syncthreads();    // the ONLY barrier

    #pragma unroll 1    // I$: keep body small (R7 lesson)
    for (int tc = 0; tc < 2; ++tc) {
        #pragma unroll
        for (int ti = 0; ti < 8; ++ti) {
            const int t = tc * 8 + ti;
            v8s B0 = *(const v8s*)(&eb[0] + rb0 + t * 1024);
            v8s B1 = *(const v8s*)(&eb[0] + rb1 + t * 1024);
            const float mh = -hl[t * 16 + l15];
            #pragma unroll
            for (int rt = 0; rt < 4; ++rt) {
                v4f c = {mh, mh, mh, mh};
                c = __builtin_amdgcn_mfma_f32_16x16x32_bf16(A[rt][0], B0, c, 0, 0, 0);
                c = __builtin_amdgcn_mfma_f32_16x16x32_bf16(A[rt][1], B1, c, 0, 0, 0);
                if (!PUSH) {
                    #pragma unroll
                    for (int r = 0; r < 4; ++r) best[rt][r] = fmaxf(best[rt][r], c[r]);
                } else {
                    bool a0 = c[0] > vm[rt][0];
                    bool a1 = c[1] > vm[rt][1];
                    bool a2 = c[2] > vm[rt][2];
                    bool a3 = c[3] > vm[rt][3];
                    if (a0 | a1 | a2 | a3) {
                        const int code = code0 + t * 16 + l15;
                        const int row0 = rowBase + rt*16 + q*4;
                        #pragma unroll
                        for (int r = 0; r < 4; ++r) {
                            if (c[r] > vm[rt][r]) {
                                int s = atomicAdd(&cnt[row0 + r], 1);
                                if (s < CAND_CAP) cand[(row0 + r) * CAND_CAP + s] = code;
                            }
                        }
                    }
                }
            }
        }
    }

    if (!PUSH) {
        #pragma unroll
        for (int rt = 0; rt < 4; ++rt)
            #pragma unroll
            for (int r = 0; r < 4; ++r) {
                float v = best[rt][r];
                v = fmaxf(v, __shfl_xor(v, 1));
                v = fmaxf(v, __shfl_xor(v, 2));
                v = fmaxf(v, __shfl_xor(v, 4));
                v = fmaxf(v, __shfl_xor(v, 8));
                if (l15 == 0)
                    pbest[(size_t)blockIdx.y * N_ + rowBase + rt*16 + q*4 + r] = v;
            }
    }
}

// ---- Kernel 3: combine splits -> threshold, zero counters + diff scalar --
__global__ __launch_bounds__(256) void k_comb(const float* __restrict__ pbest,
                                              float* __restrict__ Vm,
                                              int* __restrict__ cnt,
                                              float* __restrict__ outDiff)
{
    int n = blockIdx.x * 256 + threadIdx.x;
    float v = -INFINITY;
    #pragma unroll
    for (int s = 0; s < CS; ++s) v = fmaxf(v, pbest[(size_t)s * N_ + n]);
    Vm[n] = v - MARGIN;
    cnt[n] = 0;
    if (n == 0) *outDiff = 0.f;
}

// ---- Kernel 4: exact fp32 rescore + outputs + diff (atomic) --------------
__global__ __launch_bounds__(64) void k_pick(
    const int* __restrict__ cnt, const int* __restrict__ cand,
    const float* __restrict__ embed, const float* __restrict__ hn,
    const float* __restrict__ ze, float* __restrict__ out0,
    float* __restrict__ outIdx, float* __restrict__ outDiff)
{
    const int tid = threadIdx.x;
    const int n   = blockIdx.x * 64 + tid;

    float4 zr[16];
    const float4* zp = (const float4*)(ze + (size_t)n * D_);
    #pragma unroll
    for (int i = 0; i < 16; ++i) zr[i] = zp[i];

    const int m = cnt[n];
    float best = -INFINITY;
    int   bidx = 0x7fffffff;
    if (m == 0 || m > CAND_CAP) {
        // safety net: screen anomaly -> full exact scan, ascending k (== R2)
        for (int k = 0; k < K_; ++k) {
            float s = exact_score(zr, embed, hn[k], k);
            if (s > best) { best = s; bidx = k; }
        }
    } else {
        for (int i = 0; i < m; ++i) {
            int k = cand[n * CAND_CAP + i];
            float s = exact_score(zr, embed, hn[k], k);
            if (s > best || (s == best && k < bidx)) { best = s; bidx = k; }
        }
    }
    if (bidx == 0x7fffffff) bidx = 0;
    outIdx[n] = (float)bidx;

    const float4* eq = (const float4*)(embed + (size_t)bidx * D_);
    const int b = n >> 10, hw = n & 1023;
    float* o = out0 + (size_t)b * (D_ * HW_) + hw;

    float local = 0.f;
    #pragma unroll
    for (int d4 = 0; d4 < 16; ++d4) {
        float4 e = eq[d4], zv = zr[d4];
        float dx = e.x - zv.x, dy = e.y - zv.y, dz = e.z - zv.z, dw = e.w - zv.w;
        local += dx*dx + dy*dy + dz*dz + dw*dw;
        o[(4*d4 + 0) * HW_] = e.x;
        o[(4*d4 + 1) * HW_] = e.y;
        o[(4*d4 + 2) * HW_] = e.z;
        o[(4*d4 + 3) * HW_] = e.w;
    }

    local += __shfl_xor(local, 1);
    local += __shfl_xor(local, 2);
    local += __shfl_xor(local, 4);
    local += __shfl_xor(local, 8);
    local += __shfl_xor(local, 16);
    local += __shfl_xor(local, 32);
    if (tid == 0) atomicAdd(outDiff, local * (12.5f / (float)(N_ * D_)));
}

extern "C" void kernel_launch(void* const* d_in, const int* in_sizes, int n_in,
                              void* d_out, int out_size, void* d_ws, size_t ws_size,
                              hipStream_t stream)
{
    const float* z     = (const float*)d_in[0];
    const float* pw    = (const float*)d_in[1];
    const float* pb    = (const float*)d_in[2];
    const float* gamma = (const float*)d_in[3];
    const float* beta  = (const float*)d_in[4];
    const float* rmean = (const float*)d_in[5];
    const float* rvar  = (const float*)d_in[6];
    const float* embed = (const float*)d_in[7];

    float* out = (float*)d_out;
    float* out0    = out;                     // [B,D,H,W]
    float* outDiff = out + (size_t)N_ * D_;   // scalar
    float* outIdx  = outDiff + 1;             // [B,H,W]

    // Workspace layout
    float* ws    = (float*)d_ws;
    float* ze    = ws;                                   // N*64 f   (4 MB)
    short* zbfT  = (short*)(ze + (size_t)N_ * D_);       // N*64 s   (2 MB, tiled)
    short* ebs   = zbfT + (size_t)N_ * D_;               // K*64 s   (1 MB)
    float* hn    = (float*)(ebs + (size_t)K_ * D_);      // K        (32 KB)
    float* pbest = hn + K_;                              // CS*N     (2 MB)
    float* Vm    = pbest + (size_t)CS * N_;              // N        (64 KB)
    int*   cnt   = (int*)(Vm + N_);                      // N        (64 KB)
    int*   cand  = cnt + N_;                             // N*32     (2 MB)

    k_projprep<<<256 + 512, 256, 0, stream>>>(z, pw, pb, gamma, beta, rmean,
                                              rvar, embed, ze, zbfT, ebs, hn);
    k_sweep<false><<<dim3(N_ / ROWS_PB, CS), 256, 0, stream>>>(
        zbfT, ebs, hn, pbest, nullptr, nullptr, nullptr);
    k_comb <<<N_ / 256, 256, 0, stream>>>(pbest, Vm, cnt, outDiff);
    k_sweep<true><<<dim3(N_ / ROWS_PB, CS), 256, 0, stream>>>(
        zbfT, ebs, hn, pbest, Vm, cnt, cand);
    k_pick <<<N_ / 64, 64, 0, stream>>>(cnt, cand, embed, hn, ze, out0,
                                        outIdx, outDiff);
}

// Round 15
// 147.667 us; speedup vs baseline: 1.1757x; 1.0675x over previous
//
#include <hip/hip_runtime.h>
#include <math.h>

// Problem constants
#define B_   16
#define C_   128
#define H_   32
#define W_   32
#define D_   64
#define K_   8192
#define HW_  (H_*W_)       // 1024
#define N_   (B_*HW_)      // 16384

// MFMA sweep config — whole split staged once, zero in-loop barriers (R12),
// 512-row blocks (R15: halved staging, fewer launches/tails)
#define CS      32         // code splits (grid.y)
#define CPB     (K_/CS)    // 256 codes per block
#define ROWS_PB 512        // rows per block (8 waves x 64 rows)
// Worst-case bf16 screen error bound; 0.12 margin, E[cands/row] ~ 1.9 (R5-verified).
#define MARGIN  0.12f
#define CAND_CAP 32

typedef short v8s __attribute__((ext_vector_type(8)));
typedef float v4f __attribute__((ext_vector_type(4)));

__device__ __forceinline__ short f2bf(float f) {   // RNE fp32 -> bf16
    union { float fv; unsigned u; } cv; cv.fv = f;
    unsigned u = cv.u;
    unsigned rnd = ((u >> 16) & 1u) + 0x7fffu;
    return (short)((u + rnd) >> 16);
}

// async 16B global->LDS (gfx950). Per-wave: uniform base + lane*16.
#define GLOAD_LDS16(gp, lp) __builtin_amdgcn_global_load_lds( \
    (const __attribute__((address_space(1))) unsigned int*)(gp), \
    (__attribute__((address_space(3))) unsigned int*)(lp), 16, 0, 0)

// Exact fp32 score, bit-identical to the R2 kernel that matched the reference.
__device__ __forceinline__ float exact_score(const float4* __restrict__ zr,
                                             const float* __restrict__ embed,
                                             float h, int k)
{
    const float4* ep = (const float4*)(embed + (size_t)k * D_);
    float sa = 0.f, sb = 0.f;
    #pragma unroll
    for (int d4 = 0; d4 < 16; d4 += 2) {
        float4 ea = ep[d4], eb = ep[d4 + 1];
        sa += ea.x*zr[d4].x + ea.y*zr[d4].y + ea.z*zr[d4].z + ea.w*zr[d4].w;
        sb += eb.x*zr[d4+1].x + eb.y*zr[d4+1].y + eb.z*zr[d4+1].z + eb.w*zr[d4+1].w;
    }
    return (sa + sb) - h;
}

// ---- Kernel 1 (fused): blocks [0,256): 1x1 conv+BN -> ze fp32 + zbfT bf16
//      (conflict-free staging, R14); blocks [256,768): embed -> XOR-swizzled
//      bf16 ebs + hn; first 64 prep blocks also zero cnt, block 256 zeroes
//      outDiff (R15: k_comb eliminated).
__global__ __launch_bounds__(256) void k_projprep(
    const float* __restrict__ z, const float* __restrict__ pw,
    const float* __restrict__ pb, const float* __restrict__ gamma,
    const float* __restrict__ beta, const float* __restrict__ rmean,
    const float* __restrict__ rvar, const float* __restrict__ embed,
    float* __restrict__ ze, short* __restrict__ zbfT,
    short* __restrict__ ebs, float* __restrict__ hn,
    int* __restrict__ cnt, float* __restrict__ outDiff)
{
    __shared__ float zt[128][64];   // [c][p] — straight copy of z tile (32 KB)
    __shared__ float wl[64][128];   // [d][c] — straight copy of W     (32 KB)
    const int tid = threadIdx.x;

    if (blockIdx.x >= 256) {
        // ---- prep: 512 blocks, t in [0, K*16) ----
        const int pbk = blockIdx.x - 256;
        int t = pbk * 256 + tid;
        float4 v = ((const float4*)embed)[t];
        float s = v.x*v.x + v.y*v.y + v.z*v.z + v.w*v.w;
        s += __shfl_xor(s, 1);
        s += __shfl_xor(s, 2);
        s += __shfl_xor(s, 4);
        s += __shfl_xor(s, 8);
        const int k = t >> 4, p = t & 15;
        if (p == 0) hn[k] = 0.5f * s;
        if (p < 8) {
            const int j = p ^ (k & 7);                  // XOR swizzle
            const float* src = embed + (size_t)k * D_ + j * 8;
            v8s o;
            #pragma unroll
            for (int i = 0; i < 8; ++i) o[i] = f2bf(src[i]);
            *(v8s*)(ebs + (size_t)k * D_ + p * 8) = o;
        }
        if (pbk < 64) cnt[pbk * 256 + tid] = 0;         // zero counters
        if (pbk == 0 && tid == 0) *outDiff = 0.f;       // zero diff scalar
        return;
    }

    // ---- proj: 256 blocks (fp32 tree identical to R2-lineage) ----
    const int n0  = blockIdx.x * 64;
    const int b   = n0 / HW_;
    const int hw0 = n0 % HW_;
    const float* zb = z + (size_t)b * C_ * HW_ + hw0;

    #pragma unroll
    for (int it = 0; it < 8; ++it) {
        int flat = tid + 256 * it;          // float4 units
        int c = flat >> 4, p4 = flat & 15;
        *(float4*)&zt[c][4*p4] = *(const float4*)&zb[c * HW_ + 4*p4];
    }
    #pragma unroll
    for (int it = 0; it < 8; ++it) {
        int flat = tid + 256 * it;
        int d = flat >> 5, c4i = flat & 31;
        *(float4*)&wl[d][4*c4i] = *(const float4*)&pw[d * C_ + 4*c4i];
    }
    __syncthreads();

    const int tp = tid & 15;
    const int td = tid >> 4;
    float acc[4][4] = {};
    #pragma unroll
    for (int c4 = 0; c4 < 32; ++c4) {
        float4 zq[4], wv[4];
        #pragma unroll
        for (int k = 0; k < 4; ++k) zq[k] = *(const float4*)&zt[4*c4 + k][4*tp];
        #pragma unroll
        for (int j = 0; j < 4; ++j) wv[j] = *(const float4*)&wl[4*td + j][4*c4];
        #pragma unroll
        for (int i = 0; i < 4; ++i)
            #pragma unroll
            for (int j = 0; j < 4; ++j)
                acc[i][j] += zq[0][i]*wv[j].x + zq[1][i]*wv[j].y
                           + zq[2][i]*wv[j].z + zq[3][i]*wv[j].w;
    }

    float sc[4], bi[4];
    #pragma unroll
    for (int j = 0; j < 4; ++j) {
        int d = 4*td + j;
        float s = gamma[d] / sqrtf(rvar[d] + 1e-5f);
        sc[j] = s;
        bi[j] = pb[d] * s + beta[d] - rmean[d] * s;
    }
    short* tbase = zbfT + (size_t)blockIdx.x * 4096;
    const int islot_base = (tp >> 2) * 2 + (td >> 3);
    const int lane_hi    = ((td >> 1) & 3) * 16;
    const int el0        = 4 * (td & 1);
    #pragma unroll
    for (int i = 0; i < 4; ++i) {
        int n = n0 + 4*tp + i;
        float4 o;
        o.x = acc[i][0]*sc[0] + bi[0];
        o.y = acc[i][1]*sc[1] + bi[1];
        o.z = acc[i][2]*sc[2] + bi[2];
        o.w = acc[i][3]*sc[3] + bi[3];
        *(float4*)&ze[(size_t)n * D_ + 4*td] = o;
        short4 ob;
        ob.x = f2bf(o.x); ob.y = f2bf(o.y); ob.z = f2bf(o.z); ob.w = f2bf(o.w);
        const int lane = lane_hi + ((4*tp + i) & 15);
        *(short4*)(tbase + islot_base * 512 + lane * 8 + el0) = ob;
    }
}

// ---- Kernel 2: MFMA bf16 sweep — 512 rows/block, whole split in LDS,
//      single barrier; PUSH computes Vm in-prologue from pbest (no k_comb) --
template<bool PUSH>
__global__ __launch_bounds__(512) void k_sweep(
    const short* __restrict__ zbfT, const short* __restrict__ ebs,
    const float* __restrict__ hn, float* __restrict__ pbest,
    int* __restrict__ cnt, int* __restrict__ cand)
{
    __shared__ short eb[CPB * 64];    // 32 KB — entire split, swizzled
    __shared__ float hl[CPB];         // 1 KB
    __shared__ float vml[ROWS_PB];    // 2 KB — per-row threshold (PUSH)
    const int tid  = threadIdx.x;
    const int lane = tid & 63;
    const int wv   = tid >> 6;        // [0,8)
    const int q    = lane >> 4;
    const int l15  = lane & 15;
    const int m8   = l15 & 7;
    const int rowBase = blockIdx.x * ROWS_PB + wv * 64;
    const int code0   = blockIdx.y * CPB;

    // stage entire split: linear 32 KB copy (async, no VGPR round-trip)
    {
        const char* s_ = (const char*)(ebs + (size_t)code0 * 64);
        char* l_ = (char*)&eb[0];
        #pragma unroll
        for (int i = 0; i < 4; ++i) {
            int seg = (wv * 4 + i) * 1024 + lane * 16;
            GLOAD_LDS16(s_ + seg, l_ + seg);
        }
        if (tid < CPB) hl[tid] = hn[code0 + tid];
    }

    // PUSH: cooperative Vm: thread tid owns row blockIdx.x*512 + tid
    if (PUSH) {
        float v = -INFINITY;
        const int row = blockIdx.x * ROWS_PB + tid;
        #pragma unroll
        for (int s = 0; s < CS; ++s) v = fmaxf(v, pbest[(size_t)s * N_ + row]);
        vml[tid] = v - MARGIN;
    }

    // A fragments from tiled zbfT: 8 coalesced b128 per lane
    const short* aw = zbfT + (size_t)(blockIdx.x * 8 + wv) * 4096;
    v8s A[4][2];
    #pragma unroll
    for (int i = 0; i < 8; ++i)
        A[i >> 1][i & 1] = *(const v8s*)(aw + i * 512 + lane * 8);

    // lane-constant swizzled LDS read offsets (shorts)
    const int rb0 = l15 * 64 + ((q ^ m8) * 8);
    const int rb1 = l15 * 64 + (((q ^ m8) ^ 4) * 8);

    __syncthreads();    // the ONLY barrier

    float best[4][4];
    float vm[4][4];
    if (PUSH) {
        #pragma unroll
        for (int rt = 0; rt < 4; ++rt)
            #pragma unroll
            for (int r = 0; r < 4; ++r)
                vm[rt][r] = vml[wv * 64 + rt*16 + q*4 + r];
    } else {
        #pragma unroll
        for (int rt = 0; rt < 4; ++rt)
            #pragma unroll
            for (int r = 0; r < 4; ++r) best[rt][r] = -INFINITY;
    }

    #pragma unroll 1    // I$: keep body small (R7 lesson)
    for (int tc = 0; tc < 2; ++tc) {
        #pragma unroll
        for (int ti = 0; ti < 8; ++ti) {
            const int t = tc * 8 + ti;
            v8s B0 = *(const v8s*)(&eb[0] + rb0 + t * 1024);
            v8s B1 = *(const v8s*)(&eb[0] + rb1 + t * 1024);
            const float mh = -hl[t * 16 + l15];
            #pragma unroll
            for (int rt = 0; rt < 4; ++rt) {
                v4f c = {mh, mh, mh, mh};
                c = __builtin_amdgcn_mfma_f32_16x16x32_bf16(A[rt][0], B0, c, 0, 0, 0);
                c = __builtin_amdgcn_mfma_f32_16x16x32_bf16(A[rt][1], B1, c, 0, 0, 0);
                if (!PUSH) {
                    #pragma unroll
                    for (int r = 0; r < 4; ++r) best[rt][r] = fmaxf(best[rt][r], c[r]);
                } else {
                    bool a0 = c[0] > vm[rt][0];
                    bool a1 = c[1] > vm[rt][1];
                    bool a2 = c[2] > vm[rt][2];
                    bool a3 = c[3] > vm[rt][3];
                    if (a0 | a1 | a2 | a3) {
                        const int code = code0 + t * 16 + l15;
                        const int row0 = rowBase + rt*16 + q*4;
                        #pragma unroll
                        for (int r = 0; r < 4; ++r) {
                            if (c[r] > vm[rt][r]) {
                                int s = atomicAdd(&cnt[row0 + r], 1);
                                if (s < CAND_CAP) cand[(row0 + r) * CAND_CAP + s] = code;
                            }
                        }
                    }
                }
            }
        }
    }

    if (!PUSH) {
        #pragma unroll
        for (int rt = 0; rt < 4; ++rt)
            #pragma unroll
            for (int r = 0; r < 4; ++r) {
                float v = best[rt][r];
                v = fmaxf(v, __shfl_xor(v, 1));
                v = fmaxf(v, __shfl_xor(v, 2));
                v = fmaxf(v, __shfl_xor(v, 4));
                v = fmaxf(v, __shfl_xor(v, 8));
                if (l15 == 0)
                    pbest[(size_t)blockIdx.y * N_ + rowBase + rt*16 + q*4 + r] = v;
            }
    }
}

// ---- Kernel 3: exact fp32 rescore + outputs + diff (atomic) --------------
__global__ __launch_bounds__(64) void k_pick(
    const int* __restrict__ cnt, const int* __restrict__ cand,
    const float* __restrict__ embed, const float* __restrict__ hn,
    const float* __restrict__ ze, float* __restrict__ out0,
    float* __restrict__ outIdx, float* __restrict__ outDiff)
{
    const int tid = threadIdx.x;
    const int n   = blockIdx.x * 64 + tid;

    float4 zr[16];
    const float4* zp = (const float4*)(ze + (size_t)n * D_);
    #pragma unroll
    for (int i = 0; i < 16; ++i) zr[i] = zp[i];

    const int m = cnt[n];
    float best = -INFINITY;
    int   bidx = 0x7fffffff;
    if (m == 0 || m > CAND_CAP) {
        // safety net: screen anomaly -> full exact scan, ascending k (== R2)
        for (int k = 0; k < K_; ++k) {
            float s = exact_score(zr, embed, hn[k], k);
            if (s > best) { best = s; bidx = k; }
        }
    } else {
        for (int i = 0; i < m; ++i) {
            int k = cand[n * CAND_CAP + i];
            float s = exact_score(zr, embed, hn[k], k);
            if (s > best || (s == best && k < bidx)) { best = s; bidx = k; }
        }
    }
    if (bidx == 0x7fffffff) bidx = 0;
    outIdx[n] = (float)bidx;

    const float4* eq = (const float4*)(embed + (size_t)bidx * D_);
    const int b = n >> 10, hw = n & 1023;
    float* o = out0 + (size_t)b * (D_ * HW_) + hw;

    float local = 0.f;
    #pragma unroll
    for (int d4 = 0; d4 < 16; ++d4) {
        float4 e = eq[d4], zv = zr[d4];
        float dx = e.x - zv.x, dy = e.y - zv.y, dz = e.z - zv.z, dw = e.w - zv.w;
        local += dx*dx + dy*dy + dz*dz + dw*dw;
        o[(4*d4 + 0) * HW_] = e.x;
        o[(4*d4 + 1) * HW_] = e.y;
        o[(4*d4 + 2) * HW_] = e.z;
        o[(4*d4 + 3) * HW_] = e.w;
    }

    local += __shfl_xor(local, 1);
    local += __shfl_xor(local, 2);
    local += __shfl_xor(local, 4);
    local += __shfl_xor(local, 8);
    local += __shfl_xor(local, 16);
    local += __shfl_xor(local, 32);
    if (tid == 0) atomicAdd(outDiff, local * (12.5f / (float)(N_ * D_)));
}

extern "C" void kernel_launch(void* const* d_in, const int* in_sizes, int n_in,
                              void* d_out, int out_size, void* d_ws, size_t ws_size,
                              hipStream_t stream)
{
    const float* z     = (const float*)d_in[0];
    const float* pw    = (const float*)d_in[1];
    const float* pb    = (const float*)d_in[2];
    const float* gamma = (const float*)d_in[3];
    const float* beta  = (const float*)d_in[4];
    const float* rmean = (const float*)d_in[5];
    const float* rvar  = (const float*)d_in[6];
    const float* embed = (const float*)d_in[7];

    float* out = (float*)d_out;
    float* out0    = out;                     // [B,D,H,W]
    float* outDiff = out + (size_t)N_ * D_;   // scalar
    float* outIdx  = outDiff + 1;             // [B,H,W]

    // Workspace layout
    float* ws    = (float*)d_ws;
    float* ze    = ws;                                   // N*64 f   (4 MB)
    short* zbfT  = (short*)(ze + (size_t)N_ * D_);       // N*64 s   (2 MB, tiled)
    short* ebs   = zbfT + (size_t)N_ * D_;               // K*64 s   (1 MB)
    float* hn    = (float*)(ebs + (size_t)K_ * D_);      // K        (32 KB)
    float* pbest = hn + K_;                              // CS*N     (2 MB)
    int*   cnt   = (int*)(pbest + (size_t)CS * N_);      // N        (64 KB)
    int*   cand  = cnt + N_;                             // N*32     (2 MB)

    k_projprep<<<256 + 512, 256, 0, stream>>>(z, pw, pb, gamma, beta, rmean,
                                              rvar, embed, ze, zbfT, ebs, hn,
                                              cnt, outDiff);
    k_sweep<false><<<dim3(N_ / ROWS_PB, CS), 512, 0, stream>>>(
        zbfT, ebs, hn, pbest, nullptr, nullptr);
    k_sweep<true><<<dim3(N_ / ROWS_PB, CS), 512, 0, stream>>>(
        zbfT, ebs, hn, pbest, cnt, cand);
    k_pick <<<N_ / 64, 64, 0, stream>>>(cnt, cand, embed, hn, ze, out0,
                                        outIdx, outDiff);
}